// Round 1
// baseline (2712.136 us; speedup 1.0000x reference)
//
#include <hip/hip_runtime.h>
#include <math.h>

#define HIDDEN 1024
#define BATCH 32
#define SEQ 2048
#define MTOT (BATCH * SEQ)   // 65536 rows

// ---------------------------------------------------------------------------
// Kernel 1: fused score GEMM.
// scores[m] = sum_n v[n] * tanh( sum_h enc[m,h]*W[n,h] + dec[b(m),n] )
// Tiled fp32 GEMM: 64x64 tile, BK=16, 256 threads, 4x4 micro-tile per thread.
// Each block covers a 64-N slice; partial v-weighted tanh sums are atomically
// added into scores[m] (scores zeroed by hipMemsetAsync before launch).
// ---------------------------------------------------------------------------
__global__ __launch_bounds__(256) void score_gemm(
    const float* __restrict__ enc,   // [MTOT, HIDDEN]
    const float* __restrict__ W,     // [HIDDEN(out), HIDDEN(in)]
    const float* __restrict__ dec,   // [BATCH, HIDDEN]
    const float* __restrict__ v,     // [HIDDEN]
    float* __restrict__ scores)      // [MTOT]
{
    __shared__ float As[16][64 + 1];
    __shared__ float Bs[16][64 + 1];

    const int tid = threadIdx.x;
    const int m0 = (blockIdx.x >> 4) * 64;   // 1024 M tiles
    const int n0 = (blockIdx.x & 15) * 64;   // 16 N tiles
    const int ty = tid >> 4;                 // 0..15 (row group)
    const int tx = tid & 15;                 // 0..15 (col group)

    const int lr = tid >> 2;                 // 0..63: row within tile (loads)
    const int lc = tid & 3;                  // 0..3 : float4 col (loads)

    float acc[4][4] = {};

    for (int k0 = 0; k0 < HIDDEN; k0 += 16) {
        float4 a = *(const float4*)&enc[(size_t)(m0 + lr) * HIDDEN + k0 + lc * 4];
        float4 b = *(const float4*)&W  [(size_t)(n0 + lr) * HIDDEN + k0 + lc * 4];
        __syncthreads();   // protect previous iteration's LDS reads
        As[lc * 4 + 0][lr] = a.x; As[lc * 4 + 1][lr] = a.y;
        As[lc * 4 + 2][lr] = a.z; As[lc * 4 + 3][lr] = a.w;
        Bs[lc * 4 + 0][lr] = b.x; Bs[lc * 4 + 1][lr] = b.y;
        Bs[lc * 4 + 2][lr] = b.z; Bs[lc * 4 + 3][lr] = b.w;
        __syncthreads();
        #pragma unroll
        for (int k = 0; k < 16; ++k) {
            float4 av = *(const float4*)&As[k][ty * 4];
            float4 bv = *(const float4*)&Bs[k][tx * 4];
            float aa[4] = {av.x, av.y, av.z, av.w};
            float bb[4] = {bv.x, bv.y, bv.z, bv.w};
            #pragma unroll
            for (int i = 0; i < 4; ++i)
                #pragma unroll
                for (int j = 0; j < 4; ++j)
                    acc[i][j] = fmaf(aa[i], bb[j], acc[i][j]);
        }
    }

    // Epilogue: tanh(acc + dec) * v, reduce over this block's 64 N columns.
    float rowpart[4];
    #pragma unroll
    for (int i = 0; i < 4; ++i) {
        const int m = m0 + ty * 4 + i;
        const int b = m >> 11;               // m / SEQ
        float rp = 0.f;
        #pragma unroll
        for (int j = 0; j < 4; ++j) {
            const int n = n0 + tx * 4 + j;
            float t = tanhf(acc[i][j] + dec[b * HIDDEN + n]);
            rp = fmaf(t, v[n], rp);
        }
        rowpart[i] = rp;
    }
    // Reduce across the 16 tx lanes (tx = low 4 bits of lane id).
    #pragma unroll
    for (int off = 1; off <= 8; off <<= 1)
        #pragma unroll
        for (int i = 0; i < 4; ++i)
            rowpart[i] += __shfl_xor(rowpart[i], off, 64);

    if (tx == 0) {
        #pragma unroll
        for (int i = 0; i < 4; ++i)
            atomicAdd(&scores[m0 + ty * 4 + i], rowpart[i]);
    }
}

// ---------------------------------------------------------------------------
// Kernel 2: softmax over SEQ per batch row. One 256-thread block per batch.
// Writes weights directly into the output slab.
// ---------------------------------------------------------------------------
__global__ __launch_bounds__(256) void softmax_k(
    const float* __restrict__ scores,  // [MTOT]
    float* __restrict__ wts)           // [BATCH, SEQ] (output region)
{
    __shared__ float redmax[4];
    __shared__ float redsum[4];
    const int b = blockIdx.x;
    const int tid = threadIdx.x;
    const float* row = scores + b * SEQ;

    float vals[8];
    float lmax = -1e30f;
    #pragma unroll
    for (int j = 0; j < 8; ++j) {
        vals[j] = row[tid + j * 256];
        lmax = fmaxf(lmax, vals[j]);
    }
    #pragma unroll
    for (int off = 1; off < 64; off <<= 1)
        lmax = fmaxf(lmax, __shfl_xor(lmax, off, 64));
    if ((tid & 63) == 0) redmax[tid >> 6] = lmax;
    __syncthreads();
    const float gmax = fmaxf(fmaxf(redmax[0], redmax[1]),
                             fmaxf(redmax[2], redmax[3]));

    float lsum = 0.f;
    #pragma unroll
    for (int j = 0; j < 8; ++j) {
        vals[j] = expf(vals[j] - gmax);
        lsum += vals[j];
    }
    #pragma unroll
    for (int off = 1; off < 64; off <<= 1)
        lsum += __shfl_xor(lsum, off, 64);
    if ((tid & 63) == 0) redsum[tid >> 6] = lsum;
    __syncthreads();
    const float inv = 1.f / (redsum[0] + redsum[1] + redsum[2] + redsum[3]);

    #pragma unroll
    for (int j = 0; j < 8; ++j)
        wts[b * SEQ + tid + j * 256] = vals[j] * inv;
}

// ---------------------------------------------------------------------------
// Kernel 3: context[b,h] = sum_s w[b,s] * enc[b,s,h].
// Grid = BATCH * 8 blocks; block covers a 128-wide h-chunk.
// 256 threads = 4 s-offsets x 64 h-pairs (float2 per thread).
// ---------------------------------------------------------------------------
__global__ __launch_bounds__(256) void context_k(
    const float* __restrict__ enc,   // [MTOT, HIDDEN]
    const float* __restrict__ w,     // [BATCH, SEQ]
    float* __restrict__ ctx)         // [BATCH, HIDDEN]
{
    const int b     = blockIdx.x >> 3;
    const int chunk = blockIdx.x & 7;          // 8 chunks of 128 h
    const int sOff  = threadIdx.x >> 6;        // 0..3
    const int hp    = threadIdx.x & 63;        // 0..63
    const int h     = chunk * 128 + hp * 2;

    float2 acc = {0.f, 0.f};
    for (int s = sOff; s < SEQ; s += 4) {
        const float ws = w[b * SEQ + s];
        const float2 e = *(const float2*)&enc[(size_t)(b * SEQ + s) * HIDDEN + h];
        acc.x = fmaf(ws, e.x, acc.x);
        acc.y = fmaf(ws, e.y, acc.y);
    }

    __shared__ float2 red[4][64];
    red[sOff][hp] = acc;
    __syncthreads();
    if (sOff == 0) {
        float2 r = red[0][hp];
        #pragma unroll
        for (int t = 1; t < 4; ++t) {
            r.x += red[t][hp].x;
            r.y += red[t][hp].y;
        }
        ctx[b * HIDDEN + h]     = r.x;
        ctx[b * HIDDEN + h + 1] = r.y;
    }
}

// ---------------------------------------------------------------------------
extern "C" void kernel_launch(void* const* d_in, const int* in_sizes, int n_in,
                              void* d_out, int out_size, void* d_ws, size_t ws_size,
                              hipStream_t stream) {
    const float* dec = (const float*)d_in[0];   // [32, 1024]
    const float* enc = (const float*)d_in[1];   // [32, 2048, 1024]
    const float* W   = (const float*)d_in[2];   // [1024, 1024]
    const float* v   = (const float*)d_in[3];   // [1, 1024]

    float* out = (float*)d_out;
    float* ctx = out;                 // [32, 1024]  -> offset 0
    float* wts = out + BATCH * HIDDEN; // [32, 2048] -> offset 32768

    float* scores = (float*)d_ws;     // [MTOT] fp32 scratch

    hipMemsetAsync(d_ws, 0, MTOT * sizeof(float), stream);

    score_gemm<<<dim3(16384), dim3(256), 0, stream>>>(enc, W, dec, v, scores);
    softmax_k <<<dim3(BATCH), dim3(256), 0, stream>>>(scores, wts);
    context_k <<<dim3(BATCH * 8), dim3(256), 0, stream>>>(enc, wts, ctx);
}

// Round 2
// 353.789 us; speedup vs baseline: 7.6660x; 7.6660x over previous
//
#include <hip/hip_runtime.h>
#include <hip/hip_bf16.h>
#include <math.h>

#define HIDDEN 1024
#define BATCH 32
#define SEQ 2048
#define MTOT (BATCH * SEQ)   // 65536 rows

typedef __attribute__((ext_vector_type(8))) short          bf16x8;
typedef __attribute__((ext_vector_type(8))) unsigned short ushort8;
typedef __attribute__((ext_vector_type(4))) float          f32x4;

#define GLOAD_LDS16(g, l) __builtin_amdgcn_global_load_lds( \
    (const __attribute__((address_space(1))) void*)(g),      \
    (__attribute__((address_space(3))) void*)(l), 16, 0, 0)

// ---------------------------------------------------------------------------
// fp32 -> bf16 (RNE) bulk conversion, 8 elems/thread/iter, 16B stores.
// ---------------------------------------------------------------------------
__global__ __launch_bounds__(256) void f32_to_bf16_k(
    const float* __restrict__ in, unsigned short* __restrict__ out, int n8)
{
    for (int i = blockIdx.x * blockDim.x + threadIdx.x; i < n8;
         i += gridDim.x * blockDim.x) {
        float4 a = ((const float4*)in)[(size_t)i * 2];
        float4 b = ((const float4*)in)[(size_t)i * 2 + 1];
        float va[8] = {a.x, a.y, a.z, a.w, b.x, b.y, b.z, b.w};
        ushort8 r;
        #pragma unroll
        for (int j = 0; j < 8; ++j) {
            unsigned u = __float_as_uint(va[j]);
            unsigned rnd = u + 0x7FFFu + ((u >> 16) & 1u);   // round-nearest-even
            r[j] = (unsigned short)(rnd >> 16);
        }
        *(ushort8*)&out[(size_t)i * 8] = r;
    }
}

// ---------------------------------------------------------------------------
// MFMA score GEMM (m97 structure): 128x128 tile, BK=32, 256 thr = 4 waves,
// each wave a 64x64 sub-tile = 4x4 frags of 16x16x32 bf16 MFMA.
// Epilogue: partial = sum_n v[n]*tanh(acc + dec[b,n]) over this block's 128
// N-columns; shfl-reduce across the 16 frag columns; atomicAdd into scores.
// ---------------------------------------------------------------------------
__global__ __launch_bounds__(256) void score_gemm_mfma(
    const unsigned short* __restrict__ encb,  // [MTOT][HIDDEN] bf16
    const unsigned short* __restrict__ Wb,    // [HIDDEN][HIDDEN] bf16 (out,in)
    const float* __restrict__ dec,            // [BATCH][HIDDEN]
    const float* __restrict__ v,              // [HIDDEN]
    float* __restrict__ scores)               // [MTOT], pre-zeroed
{
    __shared__ unsigned short As[128][32];    // 8 KiB
    __shared__ unsigned short Bs[128][32];    // 8 KiB

    const int tid  = threadIdx.x;
    const int wid  = tid >> 6;
    const int lane = tid & 63;
    const int m0   = (blockIdx.x >> 3) * 128;   // 512 M-tiles
    const int n0   = (blockIdx.x & 7) * 128;    // 8 N-tiles
    const int wm   = (wid >> 1) * 64;           // wave sub-tile origin
    const int wn   = (wid & 1) * 64;

    const int lr = lane & 15;            // frag row/col
    const int kb = (lane >> 4) * 8;      // frag k-offset (bf16 elems)

    f32x4 acc[4][4] = {};

    for (int k0 = 0; k0 < HIDDEN; k0 += 32) {
        __syncthreads();   // previous tile's LDS reads done
        // stage: 512 16B-chunks per tile; chunk ch -> row=ch>>2, khalf=ch&3
        #pragma unroll
        for (int c = 0; c < 2; ++c) {
            const int chw  = c * 256 + wid * 64;       // wave-uniform chunk base
            const int ch   = chw + lane;               // per-lane chunk
            const int row  = ch >> 2, kh = (ch & 3) * 8;
            GLOAD_LDS16(&encb[(size_t)(m0 + row) * HIDDEN + k0 + kh],
                        (char*)&As[0][0] + chw * 16);
            GLOAD_LDS16(&Wb  [(size_t)(n0 + row) * HIDDEN + k0 + kh],
                        (char*)&Bs[0][0] + chw * 16);
        }
        __syncthreads();   // drains vmcnt(0): tile resident

        bf16x8 af[4], bf[4];
        #pragma unroll
        for (int f = 0; f < 4; ++f)
            af[f] = *(const bf16x8*)&As[wm + f * 16 + lr][kb];
        #pragma unroll
        for (int f = 0; f < 4; ++f)
            bf[f] = *(const bf16x8*)&Bs[wn + f * 16 + lr][kb];
        #pragma unroll
        for (int i = 0; i < 4; ++i)
            #pragma unroll
            for (int j = 0; j < 4; ++j)
                acc[i][j] = __builtin_amdgcn_mfma_f32_16x16x32_bf16(
                    af[i], bf[j], acc[i][j], 0, 0, 0);
    }

    // Epilogue. C/D layout: col = lane&15, row = (lane>>4)*4 + reg.
    const int rowgrp = lane >> 4;
    const int col    = lane & 15;
    #pragma unroll
    for (int fi = 0; fi < 4; ++fi) {
        #pragma unroll
        for (int r = 0; r < 4; ++r) {
            const int m = m0 + wm + fi * 16 + rowgrp * 4 + r;
            const int b = m >> 11;           // m / SEQ
            float rp = 0.f;
            #pragma unroll
            for (int fj = 0; fj < 4; ++fj) {
                const int n = n0 + wn + fj * 16 + col;
                float t = tanhf(acc[fi][fj][r] + dec[b * HIDDEN + n]);
                rp = fmaf(t, v[n], rp);
            }
            rp += __shfl_xor(rp, 1, 64);
            rp += __shfl_xor(rp, 2, 64);
            rp += __shfl_xor(rp, 4, 64);
            rp += __shfl_xor(rp, 8, 64);
            if (col == 0) atomicAdd(&scores[m], rp);
        }
    }
}

// ---------------------------------------------------------------------------
// softmax over SEQ per batch. One 256-thread block per batch row.
// ---------------------------------------------------------------------------
__global__ __launch_bounds__(256) void softmax_k(
    const float* __restrict__ scores, float* __restrict__ wts)
{
    __shared__ float redmax[4];
    __shared__ float redsum[4];
    const int b = blockIdx.x;
    const int tid = threadIdx.x;
    const float* row = scores + b * SEQ;

    float vals[8];
    float lmax = -1e30f;
    #pragma unroll
    for (int j = 0; j < 8; ++j) {
        vals[j] = row[tid + j * 256];
        lmax = fmaxf(lmax, vals[j]);
    }
    #pragma unroll
    for (int off = 1; off < 64; off <<= 1)
        lmax = fmaxf(lmax, __shfl_xor(lmax, off, 64));
    if ((tid & 63) == 0) redmax[tid >> 6] = lmax;
    __syncthreads();
    const float gmax = fmaxf(fmaxf(redmax[0], redmax[1]),
                             fmaxf(redmax[2], redmax[3]));

    float lsum = 0.f;
    #pragma unroll
    for (int j = 0; j < 8; ++j) {
        vals[j] = expf(vals[j] - gmax);
        lsum += vals[j];
    }
    #pragma unroll
    for (int off = 1; off < 64; off <<= 1)
        lsum += __shfl_xor(lsum, off, 64);
    if ((tid & 63) == 0) redsum[tid >> 6] = lsum;
    __syncthreads();
    const float inv = 1.f / (redsum[0] + redsum[1] + redsum[2] + redsum[3]);

    #pragma unroll
    for (int j = 0; j < 8; ++j)
        wts[b * SEQ + tid + j * 256] = vals[j] * inv;
}

// ---------------------------------------------------------------------------
// context[b,h] = sum_s w[b,s] * enc[b,s,h], reading the bf16 enc copy.
// Grid = 32 b x 8 h-chunks(128); thread = (sOff 0..15) x (hg 0..15, 8 bf16).
// ---------------------------------------------------------------------------
__global__ __launch_bounds__(256) void context_bf16_k(
    const unsigned short* __restrict__ encb,
    const float* __restrict__ w,
    float* __restrict__ ctx)
{
    const int b     = blockIdx.x >> 3;
    const int chunk = blockIdx.x & 7;
    const int sOff  = threadIdx.x >> 4;
    const int hg    = threadIdx.x & 15;
    const int h     = chunk * 128 + hg * 8;

    float acc[8] = {};
    for (int s = sOff; s < SEQ; s += 16) {
        const float ws = w[b * SEQ + s];
        ushort8 e = *(const ushort8*)&encb[(size_t)(b * SEQ + s) * HIDDEN + h];
        #pragma unroll
        for (int j = 0; j < 8; ++j)
            acc[j] = fmaf(ws, __uint_as_float((unsigned)e[j] << 16), acc[j]);
    }
    __shared__ float red[16][128];
    #pragma unroll
    for (int j = 0; j < 8; ++j) red[sOff][hg * 8 + j] = acc[j];
    __syncthreads();
    if (threadIdx.x < 128) {
        float r = 0.f;
        #pragma unroll
        for (int g = 0; g < 16; ++g) r += red[g][threadIdx.x];
        ctx[b * HIDDEN + chunk * 128 + threadIdx.x] = r;
    }
}

// ---------------------------------------------------------------------------
// Fallback fp32 path (round-1 kernels), used only if ws_size is too small.
// ---------------------------------------------------------------------------
__global__ __launch_bounds__(256) void score_gemm_f32(
    const float* __restrict__ enc, const float* __restrict__ W,
    const float* __restrict__ dec, const float* __restrict__ v,
    float* __restrict__ scores)
{
    __shared__ float As[16][64 + 1];
    __shared__ float Bs[16][64 + 1];
    const int tid = threadIdx.x;
    const int m0 = (blockIdx.x >> 4) * 64;
    const int n0 = (blockIdx.x & 15) * 64;
    const int ty = tid >> 4, tx = tid & 15;
    const int lr = tid >> 2, lc = tid & 3;
    float acc[4][4] = {};
    for (int k0 = 0; k0 < HIDDEN; k0 += 16) {
        float4 a = *(const float4*)&enc[(size_t)(m0 + lr) * HIDDEN + k0 + lc * 4];
        float4 b = *(const float4*)&W  [(size_t)(n0 + lr) * HIDDEN + k0 + lc * 4];
        __syncthreads();
        As[lc*4+0][lr]=a.x; As[lc*4+1][lr]=a.y; As[lc*4+2][lr]=a.z; As[lc*4+3][lr]=a.w;
        Bs[lc*4+0][lr]=b.x; Bs[lc*4+1][lr]=b.y; Bs[lc*4+2][lr]=b.z; Bs[lc*4+3][lr]=b.w;
        __syncthreads();
        #pragma unroll
        for (int k = 0; k < 16; ++k) {
            float4 av = *(const float4*)&As[k][ty * 4];
            float4 bv = *(const float4*)&Bs[k][tx * 4];
            float aa[4] = {av.x, av.y, av.z, av.w};
            float bb[4] = {bv.x, bv.y, bv.z, bv.w};
            #pragma unroll
            for (int i = 0; i < 4; ++i)
                #pragma unroll
                for (int j = 0; j < 4; ++j)
                    acc[i][j] = fmaf(aa[i], bb[j], acc[i][j]);
        }
    }
    float rowpart[4];
    #pragma unroll
    for (int i = 0; i < 4; ++i) {
        const int m = m0 + ty * 4 + i;
        const int b = m >> 11;
        float rp = 0.f;
        #pragma unroll
        for (int j = 0; j < 4; ++j) {
            const int n = n0 + tx * 4 + j;
            rp = fmaf(tanhf(acc[i][j] + dec[b * HIDDEN + n]), v[n], rp);
        }
        rowpart[i] = rp;
    }
    #pragma unroll
    for (int off = 1; off <= 8; off <<= 1)
        #pragma unroll
        for (int i = 0; i < 4; ++i)
            rowpart[i] += __shfl_xor(rowpart[i], off, 64);
    if (tx == 0)
        #pragma unroll
        for (int i = 0; i < 4; ++i)
            atomicAdd(&scores[m0 + ty * 4 + i], rowpart[i]);
}

__global__ __launch_bounds__(256) void context_f32_k(
    const float* __restrict__ enc, const float* __restrict__ w,
    float* __restrict__ ctx)
{
    const int b = blockIdx.x >> 3, chunk = blockIdx.x & 7;
    const int sOff = threadIdx.x >> 6, hp = threadIdx.x & 63;
    const int h = chunk * 128 + hp * 2;
    float2 acc = {0.f, 0.f};
    for (int s = sOff; s < SEQ; s += 4) {
        const float ws = w[b * SEQ + s];
        const float2 e = *(const float2*)&enc[(size_t)(b * SEQ + s) * HIDDEN + h];
        acc.x = fmaf(ws, e.x, acc.x);
        acc.y = fmaf(ws, e.y, acc.y);
    }
    __shared__ float2 red[4][64];
    red[sOff][hp] = acc;
    __syncthreads();
    if (sOff == 0) {
        float2 r = red[0][hp];
        #pragma unroll
        for (int t = 1; t < 4; ++t) { r.x += red[t][hp].x; r.y += red[t][hp].y; }
        ctx[b * HIDDEN + h] = r.x;
        ctx[b * HIDDEN + h + 1] = r.y;
    }
}

// ---------------------------------------------------------------------------
extern "C" void kernel_launch(void* const* d_in, const int* in_sizes, int n_in,
                              void* d_out, int out_size, void* d_ws, size_t ws_size,
                              hipStream_t stream) {
    const float* dec = (const float*)d_in[0];   // [32, 1024]
    const float* enc = (const float*)d_in[1];   // [32, 2048, 1024]
    const float* W   = (const float*)d_in[2];   // [1024, 1024]
    const float* v   = (const float*)d_in[3];   // [1, 1024]

    float* out = (float*)d_out;
    float* ctx = out;                           // [32, 1024]
    float* wts = out + BATCH * HIDDEN;          // [32, 2048]

    // workspace layout
    const size_t scores_bytes = (size_t)MTOT * sizeof(float);          // 256 KiB
    const size_t encb_bytes   = (size_t)MTOT * HIDDEN * 2;             // 128 MiB
    const size_t wb_bytes     = (size_t)HIDDEN * HIDDEN * 2;           // 2 MiB
    const size_t needed = scores_bytes + encb_bytes + wb_bytes;

    float* scores = (float*)d_ws;

    if (ws_size >= needed) {
        unsigned short* encb = (unsigned short*)((char*)d_ws + scores_bytes);
        unsigned short* Wb   = (unsigned short*)((char*)d_ws + scores_bytes + encb_bytes);

        hipMemsetAsync(scores, 0, scores_bytes, stream);
        f32_to_bf16_k<<<dim3(2048), dim3(256), 0, stream>>>(enc, encb, MTOT * HIDDEN / 8);
        f32_to_bf16_k<<<dim3(512),  dim3(256), 0, stream>>>(W,   Wb,   HIDDEN * HIDDEN / 8);
        score_gemm_mfma<<<dim3(4096), dim3(256), 0, stream>>>(encb, Wb, dec, v, scores);
        softmax_k<<<dim3(BATCH), dim3(256), 0, stream>>>(scores, wts);
        context_bf16_k<<<dim3(BATCH * 8), dim3(256), 0, stream>>>(encb, wts, ctx);
    } else {
        hipMemsetAsync(scores, 0, scores_bytes, stream);
        score_gemm_f32<<<dim3(16384), dim3(256), 0, stream>>>(enc, W, dec, v, scores);
        softmax_k<<<dim3(BATCH), dim3(256), 0, stream>>>(scores, wts);
        context_f32_k<<<dim3(BATCH * 8), dim3(256), 0, stream>>>(enc, wts, ctx);
    }
}